// Round 3
// baseline (278.525 us; speedup 1.0000x reference)
//
#include <hip/hip_runtime.h>

#define HW      (1024 * 1024)
#define HW4     (HW / 4)
#define NBINS   4096
#define NIMG    9                 // 8 input images + 1 style
#define BPI     128               // blocks per image -> 1152 blocks = 4.5/CU
#define THREADS 256
#define F4_PER_BLOCK (HW4 / BPI)  // 2048 float4 per block per channel
#define NBLOCKS (NIMG * BPI)

typedef float f4 __attribute__((ext_vector_type(4)));

// Exact searchsorted(boundaries, x, 'left'), boundaries b_j = (j+1)/8 - 1.
// Branchless binary search, exact float compares (verified absmax 0.0, R1/R2).
__device__ __forceinline__ int bin16(float x) {
    int lo = 0;
    if (0.0f < x) lo = 8;
    if ((float)(lo + 4) * 0.125f - 1.0f < x) lo += 4;
    if ((float)(lo + 2) * 0.125f - 1.0f < x) lo += 2;
    if ((float)(lo + 1) * 0.125f - 1.0f < x) lo += 1;
    return lo;
}

__device__ __forceinline__ int bin3(float r, float g, float b) {
    return bin16(r) + 16 * bin16(g) + 256 * bin16(b);
}

__device__ __forceinline__ void acc4(int* lh, f4 r, f4 g, f4 b) {
    atomicAdd(&lh[bin3(r.x, g.x, b.x)], 1);
    atomicAdd(&lh[bin3(r.y, g.y, b.y)], 1);
    atomicAdd(&lh[bin3(r.z, g.z, b.z)], 1);
    atomicAdd(&lh[bin3(r.w, g.w, b.w)], 1);
}

// LDS histogram -> skip-zero device-atomic flush -> last block computes loss.
__global__ __launch_bounds__(THREADS) void hist_loss_kernel(
        const float* __restrict__ input,   // [8,3,HW]
        const float* __restrict__ style,   // [1,3,HW]
        int* __restrict__ ghist,           // [NIMG, NBINS] (pre-zeroed)
        int* __restrict__ ctr,             // 1 int (pre-zeroed)
        float* __restrict__ out) {
    __shared__ int lh[NBINS];              // 16 KB
    __shared__ int last_flag;
    const int img = blockIdx.y;
    const int blk = blockIdx.x;
    const float* base = (img < 8) ? (input + (size_t)img * 3 * HW) : style;

    for (int i = threadIdx.x; i < NBINS; i += THREADS) lh[i] = 0;
    __syncthreads();

    const f4* c0 = (const f4*)(base);
    const f4* c1 = (const f4*)(base + HW);
    const f4* c2 = (const f4*)(base + 2 * HW);
    const int start = blk * F4_PER_BLOCK;

    // 2048 f4/channel per block over 256 threads -> 2 macro-iters of unroll-4
    // (12 nontemporal dwordx4 loads in flight per thread).
    for (int j = threadIdx.x; j < F4_PER_BLOCK; j += 4 * THREADS) {
        const int p0 = start + j;
        f4 r0 = __builtin_nontemporal_load(&c0[p0]);
        f4 r1 = __builtin_nontemporal_load(&c0[p0 + THREADS]);
        f4 r2 = __builtin_nontemporal_load(&c0[p0 + 2 * THREADS]);
        f4 r3 = __builtin_nontemporal_load(&c0[p0 + 3 * THREADS]);
        f4 g0 = __builtin_nontemporal_load(&c1[p0]);
        f4 g1 = __builtin_nontemporal_load(&c1[p0 + THREADS]);
        f4 g2 = __builtin_nontemporal_load(&c1[p0 + 2 * THREADS]);
        f4 g3 = __builtin_nontemporal_load(&c1[p0 + 3 * THREADS]);
        f4 b0 = __builtin_nontemporal_load(&c2[p0]);
        f4 b1 = __builtin_nontemporal_load(&c2[p0 + THREADS]);
        f4 b2 = __builtin_nontemporal_load(&c2[p0 + 2 * THREADS]);
        f4 b3 = __builtin_nontemporal_load(&c2[p0 + 3 * THREADS]);
        acc4(lh, r0, g0, b0);
        acc4(lh, r1, g1, b1);
        acc4(lh, r2, g2, b2);
        acc4(lh, r3, g3, b3);
    }
    __syncthreads();

    // Skip-zero device-scope atomic flush (~60-70% of bins nonzero).
    int* gh = ghist + (size_t)img * NBINS;
    for (int i = threadIdx.x; i < NBINS; i += THREADS) {
        const int v = lh[i];
        if (v) atomicAdd(&gh[i], v);
    }

    // ---- last-block-done: fold the loss reduction into this kernel ----
    __syncthreads();
    if (threadIdx.x == 0) {
        __threadfence();   // release our flush atomics before the count
        const int prev = __hip_atomic_fetch_add(ctr, 1, __ATOMIC_ACQ_REL,
                                                __HIP_MEMORY_SCOPE_AGENT);
        last_flag = (prev == NBLOCKS - 1);
    }
    __syncthreads();
    if (!last_flag) return;

    __threadfence();       // acquire: all blocks' ghist atomics now visible

    // Stage target histogram (style image) in LDS, reusing lh.
    for (int i = threadIdx.x; i < NBINS; i += THREADS)
        lh[i] = __hip_atomic_load(&ghist[8 * NBINS + i], __ATOMIC_RELAXED,
                                  __HIP_MEMORY_SCOPE_AGENT);
    __syncthreads();

    // sum |H[b][i] - tgt[i]|; bound 2*8*HW = 16.8M fits int32 (exact).
    int acc = 0;
    for (int e = threadIdx.x; e < 8 * NBINS; e += THREADS) {
        const int b = e >> 12;
        const int i = e & (NBINS - 1);
        const int c = __hip_atomic_load(&ghist[b * NBINS + i], __ATOMIC_RELAXED,
                                        __HIP_MEMORY_SCOPE_AGENT);
        const int d = c - lh[i];
        acc += (d < 0) ? -d : d;
    }
    for (int off = 32; off; off >>= 1) acc += __shfl_down(acc, off, 64);
    __shared__ int partsum[4];
    const int lane = threadIdx.x & 63;
    const int wv   = threadIdx.x >> 6;
    if (lane == 0) partsum[wv] = acc;
    __syncthreads();
    if (threadIdx.x == 0) {
        const long long t = (long long)partsum[0] + partsum[1]
                          + (long long)partsum[2] + partsum[3];
        // divide by HW * 8 * NBINS = 2^35 (exact double arithmetic)
        out[0] = (float)((double)t / 34359738368.0);
    }
}

extern "C" void kernel_launch(void* const* d_in, const int* in_sizes, int n_in,
                              void* d_out, int out_size, void* d_ws, size_t ws_size,
                              hipStream_t stream) {
    const float* input = (const float*)d_in[0];  // [8,3,1024,1024]
    const float* style = (const float*)d_in[1];  // [1,3,1024,1024]
    int* ghist = (int*)d_ws;                     // [9][4096]
    int* ctr   = ghist + NIMG * NBINS;           // 1 int

    hipMemsetAsync(d_ws, 0, (NIMG * NBINS + 1) * sizeof(int), stream);

    hipLaunchKernelGGL(hist_loss_kernel, dim3(BPI, NIMG), dim3(THREADS), 0,
                       stream, input, style, ghist, ctr, (float*)d_out);
}

// Round 4
// 179.886 us; speedup vs baseline: 1.5483x; 1.5483x over previous
//
#include <hip/hip_runtime.h>

#define HW      (1024 * 1024)
#define HW4     (HW / 4)
#define NBINS   4096
#define NIMG    9                 // 8 input images + 1 style
#define BPI     256               // blocks per image -> 2304 blocks = 9/CU exact
#define THREADS 256
#define F4_PER_BLOCK (HW4 / BPI)  // 1024 float4 per block per channel
#define NPART   (NIMG * BPI)      // 2304 partial histograms (u16)

typedef float f4 __attribute__((ext_vector_type(4)));

// Exact searchsorted(boundaries, x, 'left'), boundaries b_j = (j+1)/8 - 1.
// Branchless binary search, exact float compares (verified absmax 0.0 R1-R3).
__device__ __forceinline__ int bin16(float x) {
    int lo = 0;
    if (0.0f < x) lo = 8;
    if ((float)(lo + 4) * 0.125f - 1.0f < x) lo += 4;
    if ((float)(lo + 2) * 0.125f - 1.0f < x) lo += 2;
    if ((float)(lo + 1) * 0.125f - 1.0f < x) lo += 1;
    return lo;
}

__device__ __forceinline__ int bin3(float r, float g, float b) {
    return bin16(r) + 16 * bin16(g) + 256 * bin16(b);
}

__device__ __forceinline__ void acc4(int* lh, f4 r, f4 g, f4 b) {
    atomicAdd(&lh[bin3(r.x, g.x, b.x)], 1);
    atomicAdd(&lh[bin3(r.y, g.y, b.y)], 1);
    atomicAdd(&lh[bin3(r.z, g.z, b.z)], 1);
    atomicAdd(&lh[bin3(r.w, g.w, b.w)], 1);
}

// Per-block LDS histogram (4096 pixels/block, counts <= 4096 fit u16),
// flushed as a packed 8 KB vector store. NO device atomics, NO fences.
__global__ __launch_bounds__(THREADS) void hist_kernel(
        const float* __restrict__ input,        // [8,3,HW]
        const float* __restrict__ style,        // [1,3,HW]
        unsigned int* __restrict__ part) {      // [NIMG][BPI][NBINS/2] u16-pairs
    __shared__ int lh[NBINS];                   // 16 KB
    const int img = blockIdx.y;
    const int blk = blockIdx.x;
    const float* base = (img < 8) ? (input + (size_t)img * 3 * HW) : style;

    for (int i = threadIdx.x; i < NBINS; i += THREADS) lh[i] = 0;
    __syncthreads();

    const f4* c0 = (const f4*)(base);
    const f4* c1 = (const f4*)(base + HW);
    const f4* c2 = (const f4*)(base + 2 * HW);
    const int start = blk * F4_PER_BLOCK;

    // 1024 f4/channel over 256 threads -> 2 macro-iters of unroll-2
    // (6 dwordx4 loads in flight per thread).
    for (int j = threadIdx.x; j < F4_PER_BLOCK; j += 2 * THREADS) {
        const int p0 = start + j;
        const int p1 = p0 + THREADS;
        f4 r0 = c0[p0], g0 = c1[p0], b0 = c2[p0];
        f4 r1 = c0[p1], g1 = c1[p1], b1 = c2[p1];
        acc4(lh, r0, g0, b0);
        acc4(lh, r1, g1, b1);
    }
    __syncthreads();

    // Flush: pack 4 counts -> uint2 (8 B/thread/iter), 2 iters. Fully
    // overwrites this block's slice, so no pre-zeroing needed anywhere.
    uint2* dst = (uint2*)(part + ((size_t)img * BPI + blk) * (NBINS / 2));
    for (int i = threadIdx.x; i < NBINS / 4; i += THREADS) {
        uint2 v;
        v.x = (unsigned)lh[4 * i]     | ((unsigned)lh[4 * i + 1] << 16);
        v.y = (unsigned)lh[4 * i + 2] | ((unsigned)lh[4 * i + 3] << 16);
        dst[i] = v;
    }
}

// H2[half][img][bin] = sum of 128 partials. Grid (16 chunks, 9 imgs, 2 halves)
// = 288 blocks; coalesced u16 reads (consecutive threads -> consecutive bins).
__global__ __launch_bounds__(THREADS) void reduce_kernel(
        const unsigned short* __restrict__ part,  // [NIMG][BPI][NBINS]
        int* __restrict__ H2) {                   // [2][NIMG][NBINS]
    const int img  = blockIdx.y;
    const int half = blockIdx.z;
    const int bin  = blockIdx.x * THREADS + threadIdx.x;
    const unsigned short* p = part
        + ((size_t)img * BPI + half * (BPI / 2)) * NBINS + bin;
    int sum = 0;
#pragma unroll 16
    for (int b = 0; b < BPI / 2; ++b) sum += p[(size_t)b * NBINS];
    H2[((size_t)half * NIMG + img) * NBINS + bin] = sum;
}

// loss = sum_{b,i} | H[b][i] - H[8][i] | / 2^35, integer-exact.
__global__ __launch_bounds__(1024) void loss_kernel(
        const int* __restrict__ H2, float* __restrict__ out) {
    __shared__ int tgt_l[NBINS];
    __shared__ int partsum[16];
    const int* h0 = H2;
    const int* h1 = H2 + NIMG * NBINS;
    for (int i = threadIdx.x; i < NBINS; i += 1024)
        tgt_l[i] = h0[8 * NBINS + i] + h1[8 * NBINS + i];
    __syncthreads();

    int acc = 0;
    for (int e = threadIdx.x; e < 8 * NBINS; e += 1024) {
        const int c = h0[e] + h1[e];
        const int d = c - tgt_l[e & (NBINS - 1)];
        acc += (d < 0) ? -d : d;
    }
    for (int off = 32; off; off >>= 1) acc += __shfl_down(acc, off, 64);
    const int lane = threadIdx.x & 63;
    const int wv   = threadIdx.x >> 6;
    if (lane == 0) partsum[wv] = acc;
    __syncthreads();
    if (wv == 0) {
        int t = (lane < 16) ? partsum[lane] : 0;
        for (int off = 8; off; off >>= 1) t += __shfl_down(t, off, 64);
        if (lane == 0) {
            // divide by HW * 8 * NBINS = 2^35 (exact double arithmetic)
            out[0] = (float)((double)(long long)t / 34359738368.0);
        }
    }
}

extern "C" void kernel_launch(void* const* d_in, const int* in_sizes, int n_in,
                              void* d_out, int out_size, void* d_ws, size_t ws_size,
                              hipStream_t stream) {
    const float* input = (const float*)d_in[0];  // [8,3,1024,1024]
    const float* style = (const float*)d_in[1];  // [1,3,1024,1024]
    unsigned int* part = (unsigned int*)d_ws;    // [9][256][4096] u16 = 18.9 MB
    int* H2 = (int*)((char*)d_ws + (size_t)NPART * NBINS * sizeof(unsigned short));

    hipLaunchKernelGGL(hist_kernel, dim3(BPI, NIMG), dim3(THREADS), 0, stream,
                       input, style, part);
    hipLaunchKernelGGL(reduce_kernel, dim3(NBINS / THREADS, NIMG, 2),
                       dim3(THREADS), 0, stream,
                       (const unsigned short*)part, H2);
    hipLaunchKernelGGL(loss_kernel, dim3(1), dim3(1024), 0, stream,
                       H2, (float*)d_out);
}

// Round 5
// 173.041 us; speedup vs baseline: 1.6096x; 1.0396x over previous
//
#include <hip/hip_runtime.h>

#define HW      (1024 * 1024)
#define HW4     (HW / 4)
#define NBINS   4096
#define NIMG    9                 // 8 input images + 1 style
#define BPI     128               // 1152 blocks: all co-resident (<=2048), 1.11x tail
#define THREADS 256
#define F4_PER_BLOCK (HW4 / BPI)  // 2048 float4 per block per channel
#define RBINS   32                // bins per reduce block -> 128 reduce blocks

typedef float f4 __attribute__((ext_vector_type(4)));

// Exact searchsorted(boundaries, x, 'left'), boundaries b_j = (j+1)/8 - 1.
// Branchless binary search, exact float compares (verified absmax 0.0 R1-R4).
__device__ __forceinline__ int bin16(float x) {
    int lo = 0;
    if (0.0f < x) lo = 8;
    if ((float)(lo + 4) * 0.125f - 1.0f < x) lo += 4;
    if ((float)(lo + 2) * 0.125f - 1.0f < x) lo += 2;
    if ((float)(lo + 1) * 0.125f - 1.0f < x) lo += 1;
    return lo;
}

__device__ __forceinline__ int bin3(float r, float g, float b) {
    return bin16(r) + 16 * bin16(g) + 256 * bin16(b);
}

__device__ __forceinline__ void acc4(int* lh, f4 r, f4 g, f4 b) {
    atomicAdd(&lh[bin3(r.x, g.x, b.x)], 1);
    atomicAdd(&lh[bin3(r.y, g.y, b.y)], 1);
    atomicAdd(&lh[bin3(r.z, g.z, b.z)], 1);
    atomicAdd(&lh[bin3(r.w, g.w, b.w)], 1);
}

// Per-block LDS histogram (8192 pixels/block, counts fit u16), flushed as a
// packed 8 KB uint4 store. No device atomics, no fences, no pre-zeroing.
__global__ __launch_bounds__(THREADS) void hist_kernel(
        const float* __restrict__ input,        // [8,3,HW]
        const float* __restrict__ style,        // [1,3,HW]
        unsigned short* __restrict__ part) {    // [NIMG][BPI][NBINS] u16
    __shared__ int lh[NBINS];                   // 16 KB
    const int img = blockIdx.y;
    const int blk = blockIdx.x;
    const float* base = (img < 8) ? (input + (size_t)img * 3 * HW) : style;

    for (int i = threadIdx.x; i < NBINS; i += THREADS) lh[i] = 0;
    __syncthreads();

    const f4* c0 = (const f4*)(base);
    const f4* c1 = (const f4*)(base + HW);
    const f4* c2 = (const f4*)(base + 2 * HW);
    const int start = blk * F4_PER_BLOCK;

    // 2048 f4/channel over 256 threads -> 4 macro-iters of unroll-2
    // (6 dwordx4 loads in flight per thread).
    for (int j = threadIdx.x; j < F4_PER_BLOCK; j += 2 * THREADS) {
        const int p0 = start + j;
        const int p1 = p0 + THREADS;
        f4 r0 = c0[p0], g0 = c1[p0], b0 = c2[p0];
        f4 r1 = c0[p1], g1 = c1[p1], b1 = c2[p1];
        acc4(lh, r0, g0, b0);
        acc4(lh, r1, g1, b1);
    }
    __syncthreads();

    // Flush: pack 8 counts -> uint4 (16 B/thread/iter), 2 iters.
    uint4* dst = (uint4*)(part + ((size_t)img * BPI + blk) * NBINS);
    for (int i = threadIdx.x; i < NBINS / 8; i += THREADS) {
        uint4 v;
        v.x = (unsigned)lh[8 * i]     | ((unsigned)lh[8 * i + 1] << 16);
        v.y = (unsigned)lh[8 * i + 2] | ((unsigned)lh[8 * i + 3] << 16);
        v.z = (unsigned)lh[8 * i + 4] | ((unsigned)lh[8 * i + 5] << 16);
        v.w = (unsigned)lh[8 * i + 6] | ((unsigned)lh[8 * i + 7] << 16);
        dst[i] = v;
    }
}

// Fused reduce + per-bin |diff|: block b owns bins [32b, 32b+32). For each
// image, sum its 128 u16 partials per bin (style first -> target in LDS),
// accumulate |H - tgt| and plain-store one int per block. No atomics.
__global__ __launch_bounds__(THREADS) void reduce_loss_kernel(
        const unsigned short* __restrict__ part,  // [NIMG][BPI][NBINS]
        int* __restrict__ slots) {                // [128]
    __shared__ int red[8][RBINS];
    __shared__ int tgt[RBINS];
    const int b0   = blockIdx.x * RBINS;
    const int lane = threadIdx.x & 31;   // bin within chunk
    const int pg   = threadIdx.x >> 5;   // partial-group 0..7
    int acc = 0;

    for (int step = 0; step < NIMG; ++step) {
        const int img = (step == 0) ? 8 : step - 1;   // style first
        const unsigned short* p =
            part + ((size_t)img * BPI + pg) * NBINS + b0 + lane;
        int s = 0;
#pragma unroll 16
        for (int k = 0; k < BPI / 8; ++k)
            s += p[(size_t)(8 * k) * NBINS];
        red[pg][lane] = s;
        __syncthreads();
        if (threadIdx.x < RBINS) {
            int tot = 0;
#pragma unroll
            for (int r = 0; r < 8; ++r) tot += red[r][threadIdx.x];
            if (step == 0) {
                tgt[threadIdx.x] = tot;
            } else {
                const int d = tot - tgt[threadIdx.x];
                acc += (d < 0) ? -d : d;
            }
        }
        __syncthreads();   // guard red[] reuse
    }

    // acc lives in threads 0..31 (wave 0); other lanes hold 0.
    for (int off = 32; off; off >>= 1) acc += __shfl_down(acc, off, 64);
    if (threadIdx.x == 0) slots[blockIdx.x] = acc;
}

// 1 wave: sum 128 slots, scale by 1/2^35 (integer-exact, sum <= 16.8M).
__global__ __launch_bounds__(64) void final_kernel(
        const int* __restrict__ slots, float* __restrict__ out) {
    const int t = threadIdx.x;
    int s = slots[t] + slots[t + 64];
    for (int off = 32; off; off >>= 1) s += __shfl_down(s, off, 64);
    if (t == 0) out[0] = (float)((double)s / 34359738368.0);
}

extern "C" void kernel_launch(void* const* d_in, const int* in_sizes, int n_in,
                              void* d_out, int out_size, void* d_ws, size_t ws_size,
                              hipStream_t stream) {
    const float* input = (const float*)d_in[0];  // [8,3,1024,1024]
    const float* style = (const float*)d_in[1];  // [1,3,1024,1024]
    unsigned short* part = (unsigned short*)d_ws;          // 9*128*4096 u16 = 9.44 MB
    int* slots = (int*)((char*)d_ws +
                        (size_t)NIMG * BPI * NBINS * sizeof(unsigned short));

    hipLaunchKernelGGL(hist_kernel, dim3(BPI, NIMG), dim3(THREADS), 0, stream,
                       input, style, part);
    hipLaunchKernelGGL(reduce_loss_kernel, dim3(NBINS / RBINS), dim3(THREADS),
                       0, stream, part, slots);
    hipLaunchKernelGGL(final_kernel, dim3(1), dim3(64), 0, stream,
                       slots, (float*)d_out);
}

// Round 6
// 170.204 us; speedup vs baseline: 1.6364x; 1.0167x over previous
//
#include <hip/hip_runtime.h>

#define HW      (1024 * 1024)
#define HW4     (HW / 4)
#define NBINS   4096
#define NIMG    9                 // 8 input images + 1 style
#define BPI     128               // 1152 blocks: all co-resident, 1.11x tail
#define THREADS 256
#define F4_PER_BLOCK (HW4 / BPI)  // 2048 float4 per block per channel
#define NSTAGE  (F4_PER_BLOCK / (2 * THREADS))  // 4 pipeline stages
#define RBINS   16                // bins per reduce block -> 256 reduce blocks

typedef float f4 __attribute__((ext_vector_type(4)));

// Exact searchsorted(boundaries, x, 'left'), boundaries b_j = (j+1)/8 - 1.
// Branchless binary search, exact float compares (verified absmax 0.0 R1-R5).
__device__ __forceinline__ int bin16(float x) {
    int lo = 0;
    if (0.0f < x) lo = 8;
    if ((float)(lo + 4) * 0.125f - 1.0f < x) lo += 4;
    if ((float)(lo + 2) * 0.125f - 1.0f < x) lo += 2;
    if ((float)(lo + 1) * 0.125f - 1.0f < x) lo += 1;
    return lo;
}

__device__ __forceinline__ int bin3(float r, float g, float b) {
    return bin16(r) + 16 * bin16(g) + 256 * bin16(b);
}

__device__ __forceinline__ void acc4(int* lh, f4 r, f4 g, f4 b) {
    atomicAdd(&lh[bin3(r.x, g.x, b.x)], 1);
    atomicAdd(&lh[bin3(r.y, g.y, b.y)], 1);
    atomicAdd(&lh[bin3(r.z, g.z, b.z)], 1);
    atomicAdd(&lh[bin3(r.w, g.w, b.w)], 1);
}

// Per-block LDS histogram, explicitly software-pipelined: stage s+1's six
// float4 loads issue BEFORE stage s is consumed, so global-load latency
// overlaps the bin+ds_add chain. No device atomics, no fences, no zeroing.
__global__ __launch_bounds__(THREADS, 4) void hist_kernel(
        const float* __restrict__ input,        // [8,3,HW]
        const float* __restrict__ style,        // [1,3,HW]
        unsigned short* __restrict__ part) {    // [NIMG][BPI][NBINS] u16
    __shared__ int lh[NBINS];                   // 16 KB
    const int img = blockIdx.y;
    const int blk = blockIdx.x;
    const float* base = (img < 8) ? (input + (size_t)img * 3 * HW) : style;

    for (int i = threadIdx.x; i < NBINS; i += THREADS) lh[i] = 0;
    __syncthreads();

    const f4* c0 = (const f4*)(base);
    const f4* c1 = (const f4*)(base + HW);
    const f4* c2 = (const f4*)(base + 2 * HW);
    const int start = blk * F4_PER_BLOCK + threadIdx.x;

    f4 buf[2][6];
    auto load_stage = [&](int s, f4* d) {
        const int p0 = start + s * 2 * THREADS;
        const int p1 = p0 + THREADS;
        d[0] = c0[p0]; d[1] = c1[p0]; d[2] = c2[p0];
        d[3] = c0[p1]; d[4] = c1[p1]; d[5] = c2[p1];
    };

    load_stage(0, buf[0]);
#pragma unroll
    for (int s = 0; s < NSTAGE; ++s) {
        if (s + 1 < NSTAGE) load_stage(s + 1, buf[(s + 1) & 1]);
        f4* d = buf[s & 1];
        acc4(lh, d[0], d[1], d[2]);
        acc4(lh, d[3], d[4], d[5]);
    }
    __syncthreads();

    // Flush: pack 8 counts -> uint4 (16 B/thread/iter), 2 iters.
    uint4* dst = (uint4*)(part + ((size_t)img * BPI + blk) * NBINS);
    for (int i = threadIdx.x; i < NBINS / 8; i += THREADS) {
        uint4 v;
        v.x = (unsigned)lh[8 * i]     | ((unsigned)lh[8 * i + 1] << 16);
        v.y = (unsigned)lh[8 * i + 2] | ((unsigned)lh[8 * i + 3] << 16);
        v.z = (unsigned)lh[8 * i + 4] | ((unsigned)lh[8 * i + 5] << 16);
        v.w = (unsigned)lh[8 * i + 6] | ((unsigned)lh[8 * i + 7] << 16);
        dst[i] = v;
    }
}

// Fused reduce + per-bin |diff|: block b owns bins [16b, 16b+16). For each
// image, sum its 128 u16 partials per bin (style first -> target in LDS),
// accumulate |H - tgt| and plain-store one int per block. No atomics.
__global__ __launch_bounds__(THREADS) void reduce_loss_kernel(
        const unsigned short* __restrict__ part,  // [NIMG][BPI][NBINS]
        int* __restrict__ slots) {                // [256]
    __shared__ int red[16][RBINS];
    __shared__ int tgt[RBINS];
    const int b0   = blockIdx.x * RBINS;
    const int lane = threadIdx.x & 15;   // bin within chunk
    const int pg   = threadIdx.x >> 4;   // partial-group 0..15
    int acc = 0;

    for (int step = 0; step < NIMG; ++step) {
        const int img = (step == 0) ? 8 : step - 1;   // style first
        const unsigned short* p =
            part + ((size_t)img * BPI + pg) * NBINS + b0 + lane;
        int s = 0;
#pragma unroll 8
        for (int k = 0; k < BPI / 16; ++k)
            s += p[(size_t)(16 * k) * NBINS];
        red[pg][lane] = s;
        __syncthreads();
        if (threadIdx.x < RBINS) {
            int tot = 0;
#pragma unroll
            for (int r = 0; r < 16; ++r) tot += red[r][threadIdx.x];
            if (step == 0) {
                tgt[threadIdx.x] = tot;
            } else {
                const int d = tot - tgt[threadIdx.x];
                acc += (d < 0) ? -d : d;
            }
        }
        __syncthreads();   // guard red[] reuse
    }

    // acc lives in threads 0..15 (wave 0); other lanes hold 0.
    for (int off = 32; off; off >>= 1) acc += __shfl_down(acc, off, 64);
    if (threadIdx.x == 0) slots[blockIdx.x] = acc;
}

// 1 wave: sum 256 slots, scale by 1/2^35 (integer-exact, sum <= 16.8M).
__global__ __launch_bounds__(64) void final_kernel(
        const int* __restrict__ slots, float* __restrict__ out) {
    const int t = threadIdx.x;
    int s = slots[t] + slots[t + 64] + slots[t + 128] + slots[t + 192];
    for (int off = 32; off; off >>= 1) s += __shfl_down(s, off, 64);
    if (t == 0) out[0] = (float)((double)s / 34359738368.0);
}

extern "C" void kernel_launch(void* const* d_in, const int* in_sizes, int n_in,
                              void* d_out, int out_size, void* d_ws, size_t ws_size,
                              hipStream_t stream) {
    const float* input = (const float*)d_in[0];  // [8,3,1024,1024]
    const float* style = (const float*)d_in[1];  // [1,3,1024,1024]
    unsigned short* part = (unsigned short*)d_ws;   // 9*128*4096 u16 = 9.44 MB
    int* slots = (int*)((char*)d_ws +
                        (size_t)NIMG * BPI * NBINS * sizeof(unsigned short));

    hipLaunchKernelGGL(hist_kernel, dim3(BPI, NIMG), dim3(THREADS), 0, stream,
                       input, style, part);
    hipLaunchKernelGGL(reduce_loss_kernel, dim3(NBINS / RBINS), dim3(THREADS),
                       0, stream, part, slots);
    hipLaunchKernelGGL(final_kernel, dim3(1), dim3(64), 0, stream,
                       slots, (float*)d_out);
}